// Round 10
// baseline (161.850 us; speedup 1.0000x reference)
//
#include <hip/hip_runtime.h>
#include <hip/hip_bf16.h>

// GAT layer, round 10: EPB 4096->16384 (scatter run length 2.6->10.5 records,
// write amplification ~3.6x -> ~1.5x in k_bin); k_bin at 512 threads.
// Buckets stay 64 nodes (k_bucket occupancy win from round 9).
// N=100000, F=128, H=64, E=1.6M.

#define LEAKY 0.05f
#define BSH   6                  // nodes per bucket = 64
#define BSZ   64
#define EPB   16384              // edges per segment (hist/bin blocks)
#define MAXIT 6
#define CAPB  (MAXIT * 256)      // 1536 records fast-path cap (mean 1024, +16 sigma)
#define NBMAX 2048

using bf16x8 = __attribute__((ext_vector_type(8))) __bf16;
using f32x4  = __attribute__((ext_vector_type(4))) float;

__device__ __forceinline__ int wave_scan_incl(int v, int lane) {
#pragma unroll
    for (int off = 1; off < 64; off <<= 1) {
        int u = __shfl_up(v, off);
        if (lane >= off) v += u;
    }
    return v;
}
__device__ __forceinline__ unsigned short f2bf(float f) {   // RNE bf16
    unsigned u = __float_as_uint(f);
    return (unsigned short)((u + 0x7FFF + ((u >> 16) & 1)) >> 16);
}
__device__ __forceinline__ float bf2f(unsigned short u) {
    return __uint_as_float((unsigned)u << 16);
}
__device__ __forceinline__ bf16x8 pack8(const float* p) {
    float4 lo = *(const float4*)p;
    float4 hi = *(const float4*)(p + 4);
    bf16x8 v;
    v[0] = (__bf16)lo.x; v[1] = (__bf16)lo.y; v[2] = (__bf16)lo.z; v[3] = (__bf16)lo.w;
    v[4] = (__bf16)hi.x; v[5] = (__bf16)hi.y; v[6] = (__bf16)hi.z; v[7] = (__bf16)hi.w;
    return v;
}
__device__ __forceinline__ float leaky_exp(float t) {
    t = (t >= 0.f) ? t : LEAKY * t;
    return __expf(t);
}

// ---------------------------------------------------------------------------
// K1 (fused): blocks [0,lgrid) -> MFMA linear; blocks [lgrid,..) -> histogram.
__global__ __launch_bounds__(256) void k_linear_hist(
    const float* __restrict__ x, const float* __restrict__ fc_w,
    const float* __restrict__ a_w, const float* __restrict__ a_b,
    unsigned short* __restrict__ h0b, float* __restrict__ s_src,
    float* __restrict__ s_dst,
    const int* __restrict__ src, int* __restrict__ Hist,
    int N, int E, int NB, int lgrid)
{
    __shared__ int hist[NBMAX];

    if (blockIdx.x >= lgrid) {
        // ---- histogram over one segment of EPB edges ----
        const int seg = blockIdx.x - lgrid;
        for (int b = threadIdx.x; b < NB; b += 256) hist[b] = 0;
        __syncthreads();
        const int e0 = seg * EPB;
#pragma unroll
        for (int k = 0; k < EPB / 1024; ++k) {
            int e = e0 + k * 1024 + threadIdx.x * 4;
            if (e + 3 < E) {
                int4 s4 = *(const int4*)&src[e];
                atomicAdd(&hist[s4.x >> BSH], 1);
                atomicAdd(&hist[s4.y >> BSH], 1);
                atomicAdd(&hist[s4.z >> BSH], 1);
                atomicAdd(&hist[s4.w >> BSH], 1);
            } else {
                for (int q = e; q < E; ++q) atomicAdd(&hist[src[q] >> BSH], 1);
            }
        }
        __syncthreads();
        for (int b = threadIdx.x; b < NB; b += 256)
            Hist[seg * NB + b] = hist[b];
        return;
    }

    // ---- MFMA linear: one wave = 16 nodes ----
    const int wave = threadIdx.x >> 6, lane = threadIdx.x & 63;
    const int row = lane & 15, grp = lane >> 4;

    bf16x8 bf[4][4];
#pragma unroll
    for (int nt = 0; nt < 4; ++nt) {
        const float* wrow = fc_w + (size_t)(nt * 16 + row) * 128;
#pragma unroll
        for (int kb = 0; kb < 4; ++kb)
            bf[nt][kb] = pack8(wrow + kb * 32 + grp * 8);
    }
    float aw0[4], aw1[4];
#pragma unroll
    for (int nt = 0; nt < 4; ++nt) {
        aw0[nt] = a_w[nt * 16 + row];
        aw1[nt] = a_w[64 + nt * 16 + row];
    }
    const float ab = a_b[0];

    const int tile = blockIdx.x * 4 + wave;
    const int base = tile * 16;
    if (base >= N) return;
    const int node = min(base + row, N - 1);

    bf16x8 af[4];
#pragma unroll
    for (int kb = 0; kb < 4; ++kb)
        af[kb] = pack8(x + (size_t)node * 128 + kb * 32 + grp * 8);

    f32x4 acc[4];
#pragma unroll
    for (int nt = 0; nt < 4; ++nt) acc[nt] = (f32x4){0.f, 0.f, 0.f, 0.f};

#pragma unroll
    for (int nt = 0; nt < 4; ++nt)
#pragma unroll
        for (int kb = 0; kb < 4; ++kb)
            acc[nt] = __builtin_amdgcn_mfma_f32_16x16x32_bf16(
                af[kb], bf[nt][kb], acc[nt], 0, 0, 0);

#pragma unroll
    for (int nt = 0; nt < 4; ++nt)
#pragma unroll
        for (int r = 0; r < 4; ++r) {
            int nrow = base + grp * 4 + r;
            if (nrow < N)
                h0b[(size_t)nrow * 64 + nt * 16 + row] = f2bf(acc[nt][r]);
        }

#pragma unroll
    for (int r = 0; r < 4; ++r) {
        float p0 = 0.f, p1 = 0.f;
#pragma unroll
        for (int nt = 0; nt < 4; ++nt) {
            p0 += acc[nt][r] * aw0[nt];
            p1 += acc[nt][r] * aw1[nt];
        }
#pragma unroll
        for (int off = 1; off < 16; off <<= 1) {
            p0 += __shfl_xor(p0, off);
            p1 += __shfl_xor(p1, off);
        }
        int nrow = base + grp * 4 + r;
        if (row == 0 && nrow < N) { s_src[nrow] = p0 + ab; s_dst[nrow] = p1; }
    }
}

// ---------------------------------------------------------------------------
// K3: column scan of Hist -> Base[seg][b] (excl prefix within column) + coltot
__global__ __launch_bounds__(512) void k_colscan(
    const int* __restrict__ Hist, int* __restrict__ Base,
    int* __restrict__ coltot, int NEB, int NB)
{
    __shared__ int wsum[8];
    const int b = blockIdx.x;
    const int t = threadIdx.x, wave = t >> 6, lane = t & 63;
    int v = (t < NEB) ? Hist[t * NB + b] : 0;
    int incl = wave_scan_incl(v, lane);
    if (lane == 63) wsum[wave] = incl;
    __syncthreads();
    int woff = 0;
    for (int w = 0; w < wave; ++w) woff += wsum[w];
    if (t < NEB) Base[t * NB + b] = woff + incl - v;
    if (t == NEB - 1) coltot[b] = woff + incl;
}

// K4: chunked exclusive scan of coltot[NB] -> boff
__global__ __launch_bounds__(512) void k_boff(
    const int* __restrict__ coltot, int* __restrict__ boff, int NB, int E)
{
    __shared__ int wsum[8];
    __shared__ int s_carry;
    const int t = threadIdx.x, wave = t >> 6, lane = t & 63;
    if (t == 0) s_carry = 0;
    __syncthreads();
    for (int base = 0; base < NB; base += 512) {
        int idx = base + t;
        int orig = (idx < NB) ? coltot[idx] : 0;
        int incl = wave_scan_incl(orig, lane);
        if (lane == 63) wsum[wave] = incl;
        __syncthreads();
        int woff = 0;
        for (int w = 0; w < wave; ++w) woff += wsum[w];
        int carry = s_carry;
        if (idx < NB) boff[idx] = carry + woff + incl - orig;
        __syncthreads();
        if (t == 511) s_carry = carry + woff + incl;
        __syncthreads();
    }
    if (t == 0) boff[NB] = E;
}

// ---------------------------------------------------------------------------
// K5: bin edges; h recomputed from scores; record {dst|srclow<<24, h_bf|v_bf}
__global__ __launch_bounds__(512) void k_bin(
    const int* __restrict__ src, const int* __restrict__ dst,
    const float* __restrict__ adj,
    const float* __restrict__ s_src, const float* __restrict__ s_dst,
    const int* __restrict__ boff, const int* __restrict__ Base,
    int2* __restrict__ binned, int E, int NB)
{
    __shared__ int cur[NBMAX];
    for (int b = threadIdx.x; b < NB; b += 512)
        cur[b] = boff[b] + Base[blockIdx.x * NB + b];
    __syncthreads();
    const int e0 = blockIdx.x * EPB;
#pragma unroll
    for (int k = 0; k < EPB / 2048; ++k) {
        int e = e0 + k * 2048 + threadIdx.x * 4;
        if (e + 3 < E) {
            int4   s4 = *(const int4*)&src[e];
            int4   d4 = *(const int4*)&dst[e];
            float4 a4 = *(const float4*)&adj[e];
#pragma unroll
            for (int q = 0; q < 4; ++q) {
                int s = (&s4.x)[q], d = (&d4.x)[q];
                float h = leaky_exp(s_src[s] + s_dst[d]);
                float v = h * (&a4.x)[q];
                unsigned hv = ((unsigned)f2bf(h) << 16) | f2bf(v);
                int w0 = d | ((s & (BSZ - 1)) << 24);
                int pos = atomicAdd(&cur[s >> BSH], 1);
                binned[pos] = make_int2(w0, (int)hv);
            }
        } else {
            for (int q = e; q < E; ++q) {
                int s = src[q], d = dst[q];
                float h = leaky_exp(s_src[s] + s_dst[d]);
                float v = h * adj[q];
                unsigned hv = ((unsigned)f2bf(h) << 16) | f2bf(v);
                int w0 = d | ((s & (BSZ - 1)) << 24);
                int pos = atomicAdd(&cur[s >> BSH], 1);
                binned[pos] = make_int2(w0, (int)hv);
            }
        }
    }
}

// ---------------------------------------------------------------------------
// K6: per-bucket LDS CSR build + quad-edge fused gather.
// 256 thr / 4 waves / 64 nodes. Gather lanes: eslot=lane>>4, fq=lane&15.
__global__ __launch_bounds__(256) void k_bucket(
    const int2* __restrict__ binned, const int* __restrict__ boff,
    const unsigned short* __restrict__ h0b, float* __restrict__ out,
    float* __restrict__ inv_hsum_g, int N)
{
    __shared__ int   deg_cur[BSZ];
    __shared__ int   pref[BSZ + 1];
    __shared__ float hsumS[BSZ];
    __shared__ int2  rec[CAPB];       // {dst, val_fp32_bits}

    const int b  = blockIdx.x;
    const int lo = boff[b], hi = boff[b + 1], cnt = hi - lo;
    const int n0 = b << BSH;
    const int nn = min(BSZ, N - n0);
    const int t = threadIdx.x, wave = t >> 6, lane = t & 63;

    if (t < BSZ) { deg_cur[t] = 0; hsumS[t] = 0.f; }
    __syncthreads();

    if (cnt <= CAPB) {
        int2 r[MAXIT];
#pragma unroll
        for (int it = 0; it < MAXIT; ++it) {
            int j = lo + it * 256 + t;
            if (j < hi) r[it] = binned[j];
        }
#pragma unroll
        for (int it = 0; it < MAXIT; ++it)
            if (lo + it * 256 + t < hi)
                atomicAdd(&deg_cur[(unsigned)r[it].x >> 24], 1);
        __syncthreads();

        // single-wave scan over 64 degrees
        if (wave == 0) {
            int v = deg_cur[lane];
            int incl = wave_scan_incl(v, lane);
            pref[lane + 1] = incl;
            if (lane == 0) pref[0] = 0;
            deg_cur[lane] = incl - v;        // cursor = exclusive prefix
        }
        __syncthreads();

#pragma unroll
        for (int it = 0; it < MAXIT; ++it) {
            if (lo + it * 256 + t < hi) {
                int2 rr = r[it];
                int node = (unsigned)rr.x >> 24;
                int d    = rr.x & 0xFFFFFF;
                float hh = __uint_as_float((unsigned)rr.y & 0xFFFF0000u);
                float vv = __uint_as_float((unsigned)rr.y << 16);
                int pos = atomicAdd(&deg_cur[node], 1);
                rec[pos] = make_int2(d, __float_as_int(vv));
                atomicAdd(&hsumS[node], hh);
            }
        }
        __syncthreads();

        const int eslot = lane >> 4, fq = lane & 15;
        for (int n = wave; n < nn; n += 4) {
            const int s = pref[n], e2 = pref[n + 1];
            float a0[4] = {0.f, 0.f, 0.f, 0.f};
            float a1[4] = {0.f, 0.f, 0.f, 0.f};
            for (int base2 = s; base2 < e2; base2 += 8) {
                int idxA = base2 + eslot;
                int idxB = base2 + 4 + eslot;
                bool vA = idxA < e2, vB = idxB < e2;
                int2 rA = rec[vA ? idxA : s];
                int2 rB = rec[vB ? idxB : s];
                float valA = vA ? __int_as_float(rA.y) : 0.f;
                float valB = vB ? __int_as_float(rB.y) : 0.f;
                uint2 uA = *(const uint2*)(h0b + (size_t)rA.x * 64 + fq * 4);
                uint2 uB = *(const uint2*)(h0b + (size_t)rB.x * 64 + fq * 4);
                a0[0] += valA * __uint_as_float(uA.x << 16);
                a0[1] += valA * __uint_as_float(uA.x & 0xFFFF0000u);
                a0[2] += valA * __uint_as_float(uA.y << 16);
                a0[3] += valA * __uint_as_float(uA.y & 0xFFFF0000u);
                a1[0] += valB * __uint_as_float(uB.x << 16);
                a1[1] += valB * __uint_as_float(uB.x & 0xFFFF0000u);
                a1[2] += valB * __uint_as_float(uB.y << 16);
                a1[3] += valB * __uint_as_float(uB.y & 0xFFFF0000u);
            }
#pragma unroll
            for (int k = 0; k < 4; ++k) {
                float vv = a0[k] + a1[k];
                vv += __shfl_xor(vv, 16);
                vv += __shfl_xor(vv, 32);
                a0[k] = vv;
            }
            float inv = (e2 > s) ? 1.0f / hsumS[n] : 0.f;
            if (lane < 16) {
                float4 o;
                o.x = a0[0] * inv; o.y = a0[1] * inv;
                o.z = a0[2] * inv; o.w = a0[3] * inv;
                *(float4*)&out[(size_t)(n0 + n) * 64 + fq * 4] = o;
            }
            if (lane == 0) inv_hsum_g[n0 + n] = inv;
        }
    } else {
        // correctness-only fallback (cnt > CAPB is ~16 sigma; never expected)
        for (int n = wave; n < nn; n += 4) {
            float acc = 0.f, hs = 0.f;
            for (int j = lo; j < hi; ++j) {
                int2 rr = binned[j];
                if (((unsigned)rr.x >> 24) == (unsigned)n) {
                    hs  += __uint_as_float((unsigned)rr.y & 0xFFFF0000u);
                    acc += __uint_as_float((unsigned)rr.y << 16) *
                           bf2f(h0b[(size_t)(rr.x & 0xFFFFFF) * 64 + lane]);
                }
            }
            float inv = (hs > 0.f) ? 1.0f / hs : 0.f;
            out[(size_t)(n0 + n) * 64 + lane] = acc * inv;
            if (lane == 0) inv_hsum_g[n0 + n] = inv;
        }
    }
}

// ---------------------------------------------------------------------------
// K7: alpha[e] = h(e) * inv_hsum[src[e]]  (h recomputed; coalesced, x4)
__global__ __launch_bounds__(256) void k_alpha(
    const int* __restrict__ src, const int* __restrict__ dst,
    const float* __restrict__ s_src, const float* __restrict__ s_dst,
    const float* __restrict__ inv_hsum_g, float* __restrict__ alpha, int E)
{
    int i = blockIdx.x * 256 + threadIdx.x;
    int e = i * 4;
    if (e + 3 < E) {
        int4 s4 = *(const int4*)&src[e];
        int4 d4 = *(const int4*)&dst[e];
        float4 a;
        a.x = leaky_exp(s_src[s4.x] + s_dst[d4.x]) * inv_hsum_g[s4.x];
        a.y = leaky_exp(s_src[s4.y] + s_dst[d4.y]) * inv_hsum_g[s4.y];
        a.z = leaky_exp(s_src[s4.z] + s_dst[d4.z]) * inv_hsum_g[s4.z];
        a.w = leaky_exp(s_src[s4.w] + s_dst[d4.w]) * inv_hsum_g[s4.w];
        *(float4*)&alpha[e] = a;
    } else {
        for (; e < E; ++e)
            alpha[e] = leaky_exp(s_src[src[e]] + s_dst[dst[e]]) * inv_hsum_g[src[e]];
    }
}

// ---------------------------------------------------------------------------
extern "C" void kernel_launch(void* const* d_in, const int* in_sizes, int n_in,
                              void* d_out, int out_size, void* d_ws, size_t ws_size,
                              hipStream_t stream)
{
    const float* x    = (const float*)d_in[0];
    const int*   ei   = (const int*)d_in[1];
    const float* adj  = (const float*)d_in[2];
    const float* fc_w = (const float*)d_in[3];
    const float* a_w  = (const float*)d_in[4];
    const float* a_b  = (const float*)d_in[5];

    const int N = in_sizes[0] / 128;          // 100000
    const int E = in_sizes[2];                // 1600000
    const int* src = ei;
    const int* dst = ei + E;

    const int NB  = (N + BSZ - 1) >> BSH;     // 1563 buckets
    const int NEB = (E + EPB - 1) / EPB;      // 98 segments

    float* out   = (float*)d_out;
    float* alpha = out + (size_t)N * 64;

    char* w = (char*)d_ws;
    auto carve = [&](size_t bytes) {
        char* p = w;
        w += (bytes + 255) & ~(size_t)255;
        return p;
    };
    unsigned short* h0b = (unsigned short*)carve((size_t)N * 64 * 2);
    float* s_src   = (float*)carve((size_t)N * 4);
    float* s_dst   = (float*)carve((size_t)N * 4);
    float* inv_hs  = (float*)carve((size_t)N * 4);
    int*   Hist    = (int*)  carve((size_t)NEB * NB * 4);
    int*   Base    = (int*)  carve((size_t)NEB * NB * 4);
    int*   coltot  = (int*)  carve((size_t)NB * 4);
    int*   boff    = (int*)  carve((size_t)(NB + 1) * 4);
    int2*  binned  = (int2*) carve((size_t)E * 8);

    const int tiles = (N + 15) / 16;
    const int lgrid = (tiles + 3) / 4;         // 1563 linear blocks

    k_linear_hist<<<lgrid + NEB, 256, 0, stream>>>(
        x, fc_w, a_w, a_b, h0b, s_src, s_dst, src, Hist, N, E, NB, lgrid);
    k_colscan<<<NB, 512, 0, stream>>>(Hist, Base, coltot, NEB, NB);
    k_boff<<<1, 512, 0, stream>>>(coltot, boff, NB, E);
    k_bin<<<NEB, 512, 0, stream>>>(src, dst, adj, s_src, s_dst, boff, Base,
                                   binned, E, NB);
    k_bucket<<<NB, 256, 0, stream>>>(binned, boff, h0b, out, inv_hs, N);
    k_alpha<<<(E / 4 + 255) / 256, 256, 0, stream>>>(src, dst, s_src, s_dst,
                                                     inv_hs, alpha, E);
}

// Round 11
// 149.476 us; speedup vs baseline: 1.0828x; 1.0828x over previous
//
#include <hip/hip_runtime.h>
#include <hip/hip_bf16.h>

// GAT layer, round 11: segment-major binned layout. k_bin sorts its 4096 edges
// in LDS and streams them out fully coalesced (zero write amplification, no
// cross-block offsets -> colscan/boff/Hist/Base all deleted). k_bucket pulls
// its bucket's records from 391 short runs (random READS, L3-resident) and
// keeps the round-9 quad-gather. N=100000, F=128, H=64, E=1.6M.

#define LEAKY 0.05f
#define BSH   6                  // nodes per bucket = 64
#define BSZ   64
#define EPB   4096               // edges per segment
#define CAPB  1536               // records fast-path cap (mean 1024, +16 sigma)
#define NBMAX 2048

using bf16x8 = __attribute__((ext_vector_type(8))) __bf16;
using f32x4  = __attribute__((ext_vector_type(4))) float;

__device__ __forceinline__ int wave_scan_incl(int v, int lane) {
#pragma unroll
    for (int off = 1; off < 64; off <<= 1) {
        int u = __shfl_up(v, off);
        if (lane >= off) v += u;
    }
    return v;
}
__device__ __forceinline__ unsigned short f2bf(float f) {   // RNE bf16
    unsigned u = __float_as_uint(f);
    return (unsigned short)((u + 0x7FFF + ((u >> 16) & 1)) >> 16);
}
__device__ __forceinline__ float bf2f(unsigned short u) {
    return __uint_as_float((unsigned)u << 16);
}
__device__ __forceinline__ bf16x8 pack8(const float* p) {
    float4 lo = *(const float4*)p;
    float4 hi = *(const float4*)(p + 4);
    bf16x8 v;
    v[0] = (__bf16)lo.x; v[1] = (__bf16)lo.y; v[2] = (__bf16)lo.z; v[3] = (__bf16)lo.w;
    v[4] = (__bf16)hi.x; v[5] = (__bf16)hi.y; v[6] = (__bf16)hi.z; v[7] = (__bf16)hi.w;
    return v;
}
__device__ __forceinline__ float leaky_exp(float t) {
    t = (t >= 0.f) ? t : LEAKY * t;
    return __expf(t);
}

// ---------------------------------------------------------------------------
// K1: h0b = bf16(x @ fc_w^T) via mfma_f32_16x16x32_bf16; s_src/s_dst from regs.
__global__ __launch_bounds__(256) void k_linear_mfma(
    const float* __restrict__ x, const float* __restrict__ fc_w,
    const float* __restrict__ a_w, const float* __restrict__ a_b,
    unsigned short* __restrict__ h0b, float* __restrict__ s_src,
    float* __restrict__ s_dst, int N)
{
    const int wave = threadIdx.x >> 6, lane = threadIdx.x & 63;
    const int row = lane & 15, grp = lane >> 4;

    bf16x8 bf[4][4];
#pragma unroll
    for (int nt = 0; nt < 4; ++nt) {
        const float* wrow = fc_w + (size_t)(nt * 16 + row) * 128;
#pragma unroll
        for (int kb = 0; kb < 4; ++kb)
            bf[nt][kb] = pack8(wrow + kb * 32 + grp * 8);
    }
    float aw0[4], aw1[4];
#pragma unroll
    for (int nt = 0; nt < 4; ++nt) {
        aw0[nt] = a_w[nt * 16 + row];
        aw1[nt] = a_w[64 + nt * 16 + row];
    }
    const float ab = a_b[0];

    const int tile = blockIdx.x * 4 + wave;
    const int base = tile * 16;
    if (base >= N) return;
    const int node = min(base + row, N - 1);

    bf16x8 af[4];
#pragma unroll
    for (int kb = 0; kb < 4; ++kb)
        af[kb] = pack8(x + (size_t)node * 128 + kb * 32 + grp * 8);

    f32x4 acc[4];
#pragma unroll
    for (int nt = 0; nt < 4; ++nt) acc[nt] = (f32x4){0.f, 0.f, 0.f, 0.f};

#pragma unroll
    for (int nt = 0; nt < 4; ++nt)
#pragma unroll
        for (int kb = 0; kb < 4; ++kb)
            acc[nt] = __builtin_amdgcn_mfma_f32_16x16x32_bf16(
                af[kb], bf[nt][kb], acc[nt], 0, 0, 0);

#pragma unroll
    for (int nt = 0; nt < 4; ++nt)
#pragma unroll
        for (int r = 0; r < 4; ++r) {
            int nrow = base + grp * 4 + r;
            if (nrow < N)
                h0b[(size_t)nrow * 64 + nt * 16 + row] = f2bf(acc[nt][r]);
        }

#pragma unroll
    for (int r = 0; r < 4; ++r) {
        float p0 = 0.f, p1 = 0.f;
#pragma unroll
        for (int nt = 0; nt < 4; ++nt) {
            p0 += acc[nt][r] * aw0[nt];
            p1 += acc[nt][r] * aw1[nt];
        }
#pragma unroll
        for (int off = 1; off < 16; off <<= 1) {
            p0 += __shfl_xor(p0, off);
            p1 += __shfl_xor(p1, off);
        }
        int nrow = base + grp * 4 + r;
        if (row == 0 && nrow < N) { s_src[nrow] = p0 + ab; s_dst[nrow] = p1; }
    }
}

// ---------------------------------------------------------------------------
// K2: per-segment LDS counting sort -> coalesced binned[seg*EPB..] + SegPrefix row.
// record: {dst | srclow<<24, h_bf16<<16 | v_bf16}
__global__ __launch_bounds__(256) void k_bin(
    const int* __restrict__ src, const int* __restrict__ dst,
    const float* __restrict__ adj,
    const float* __restrict__ s_src, const float* __restrict__ s_dst,
    int2* __restrict__ binned, int* __restrict__ segpref, int E, int NB)
{
    __shared__ int  hist[NBMAX];     // counts -> exclusive prefix (in place)
    __shared__ int  cur[NBMAX];
    __shared__ int  wpart[4];
    __shared__ int2 stage[EPB];      // 32 KB

    const int t = threadIdx.x;
    const int seg = blockIdx.x;
    const int e0 = seg * EPB;
    const int segcnt = min(EPB, E - e0);

    for (int b = t; b < NB; b += 256) hist[b] = 0;
    __syncthreads();

    // load edges, build records in registers, LDS histogram
    int rw0[16], rw1[16], bkt[16];
#pragma unroll
    for (int k = 0; k < 4; ++k) {
        int e = e0 + k * 1024 + t * 4;
        if (e + 3 < E) {
            int4   s4 = *(const int4*)&src[e];
            int4   d4 = *(const int4*)&dst[e];
            float4 a4 = *(const float4*)&adj[e];
#pragma unroll
            for (int q = 0; q < 4; ++q) {
                const int i = k * 4 + q;
                int s = (&s4.x)[q], d = (&d4.x)[q];
                float h = leaky_exp(s_src[s] + s_dst[d]);
                float v = h * (&a4.x)[q];
                rw0[i] = d | ((s & (BSZ - 1)) << 24);
                rw1[i] = (int)(((unsigned)f2bf(h) << 16) | f2bf(v));
                bkt[i] = s >> BSH;
                atomicAdd(&hist[bkt[i]], 1);
            }
        } else {
#pragma unroll
            for (int q = 0; q < 4; ++q) {
                const int i = k * 4 + q;
                int ee = e + q;
                if (ee < E) {
                    int s = src[ee], d = dst[ee];
                    float h = leaky_exp(s_src[s] + s_dst[d]);
                    float v = h * adj[ee];
                    rw0[i] = d | ((s & (BSZ - 1)) << 24);
                    rw1[i] = (int)(((unsigned)f2bf(h) << 16) | f2bf(v));
                    bkt[i] = s >> BSH;
                    atomicAdd(&hist[bkt[i]], 1);
                } else bkt[i] = -1;
            }
        }
    }
    __syncthreads();

    // block exclusive scan of hist[0..NB) in place
    const int C = (NB + 255) / 256;
    const int lo = t * C, hiB = min(NB, lo + C);
    int ssum = 0;
    for (int b = lo; b < hiB; ++b) ssum += hist[b];
    const int lane = t & 63, wv = t >> 6;
    int incl = wave_scan_incl(ssum, lane);
    if (lane == 63) wpart[wv] = incl;
    __syncthreads();
    int woff = 0;
    for (int w2 = 0; w2 < wv; ++w2) woff += wpart[w2];
    int run = woff + incl - ssum;
    for (int b = lo; b < hiB; ++b) { int v = hist[b]; hist[b] = run; run += v; }
    if (t == 255) segpref[(size_t)seg * (NB + 1) + NB] = run;   // == segcnt
    __syncthreads();

    for (int b = t; b < NB; b += 256) {
        int v = hist[b];
        segpref[(size_t)seg * (NB + 1) + b] = v;
        cur[b] = v;
    }
    __syncthreads();

    // place records into sorted LDS slots
#pragma unroll
    for (int i = 0; i < 16; ++i) {
        if (bkt[i] >= 0) {
            int pos = atomicAdd(&cur[bkt[i]], 1);
            stage[pos] = make_int2(rw0[i], rw1[i]);
        }
    }
    __syncthreads();

    // stream out fully coalesced (int4 = 2 records)
    const int npair = segcnt >> 1;
    for (int j = t; j < npair; j += 256)
        *(int4*)&binned[e0 + j * 2] = *(const int4*)&stage[j * 2];
    if (t == 0 && (segcnt & 1)) binned[e0 + segcnt - 1] = stage[segcnt - 1];
}

// ---------------------------------------------------------------------------
// K3: per-bucket: collect records from NEB per-segment runs (random L3 reads),
// LDS CSR build, round-9 quad-gather. 256 thr / 4 waves / 64 nodes.
__global__ __launch_bounds__(256) void k_bucket(
    const int2* __restrict__ binned, const int* __restrict__ segpref,
    const unsigned short* __restrict__ h0b, float* __restrict__ out,
    float* __restrict__ inv_hsum_g, int N, int NEB, int NB)
{
    __shared__ int   deg_cur[BSZ];
    __shared__ int   pref[BSZ + 1];
    __shared__ float hsumS[BSZ];
    __shared__ int2  rec[CAPB];      // {dst, val_fp32_bits}

    const int b  = blockIdx.x;
    const int n0 = b << BSH;
    const int nn = min(BSZ, N - n0);
    const int t = threadIdx.x, wv = t >> 6, lane = t & 63;

    if (t < BSZ) { deg_cur[t] = 0; hsumS[t] = 0.f; }
    __syncthreads();

    // Phase A1: walk this bucket's runs (thread-per-segment): count + hsum
    int base0 = 0, len0 = 0, base1 = 0, len1 = 0;
    {
        int seg = t;
        if (seg < NEB) {
            size_t o = (size_t)seg * (NB + 1) + b;
            int st = segpref[o], en = segpref[o + 1];
            base0 = seg * EPB + st; len0 = en - st;
        }
        seg = t + 256;
        if (seg < NEB) {
            size_t o = (size_t)seg * (NB + 1) + b;
            int st = segpref[o], en = segpref[o + 1];
            base1 = seg * EPB + st; len1 = en - st;
        }
    }
    for (int i = 0; i < len0; ++i) {
        int2 rr = binned[base0 + i];
        int node = (unsigned)rr.x >> 24;
        atomicAdd(&deg_cur[node], 1);
        atomicAdd(&hsumS[node], __uint_as_float((unsigned)rr.y & 0xFFFF0000u));
    }
    for (int i = 0; i < len1; ++i) {
        int2 rr = binned[base1 + i];
        int node = (unsigned)rr.x >> 24;
        atomicAdd(&deg_cur[node], 1);
        atomicAdd(&hsumS[node], __uint_as_float((unsigned)rr.y & 0xFFFF0000u));
    }
    __syncthreads();

    // single-wave scan over 64 degrees -> pref, cursor
    if (wv == 0) {
        int v = deg_cur[lane];
        int incl = wave_scan_incl(v, lane);
        pref[lane + 1] = incl;
        if (lane == 0) pref[0] = 0;
        deg_cur[lane] = incl - v;
    }
    __syncthreads();
    const int cnt = pref[BSZ];

    if (cnt <= CAPB) {
        // Phase A2: re-walk runs (L2-hot), place into LDS CSR
        for (int i = 0; i < len0; ++i) {
            int2 rr = binned[base0 + i];
            int node = (unsigned)rr.x >> 24;
            int pos = atomicAdd(&deg_cur[node], 1);
            rec[pos] = make_int2(rr.x & 0xFFFFFF, (int)((unsigned)rr.y << 16));
        }
        for (int i = 0; i < len1; ++i) {
            int2 rr = binned[base1 + i];
            int node = (unsigned)rr.x >> 24;
            int pos = atomicAdd(&deg_cur[node], 1);
            rec[pos] = make_int2(rr.x & 0xFFFFFF, (int)((unsigned)rr.y << 16));
        }
        __syncthreads();

        // Phase B: quad-edge gather (round-9 proven layout)
        const int eslot = lane >> 4, fq = lane & 15;
        for (int n = wv; n < nn; n += 4) {
            const int s = pref[n], e2 = pref[n + 1];
            float a0[4] = {0.f, 0.f, 0.f, 0.f};
            float a1[4] = {0.f, 0.f, 0.f, 0.f};
            for (int base2 = s; base2 < e2; base2 += 8) {
                int idxA = base2 + eslot;
                int idxB = base2 + 4 + eslot;
                bool vA = idxA < e2, vB = idxB < e2;
                int2 rA = rec[vA ? idxA : s];
                int2 rB = rec[vB ? idxB : s];
                float valA = vA ? __int_as_float(rA.y) : 0.f;
                float valB = vB ? __int_as_float(rB.y) : 0.f;
                uint2 uA = *(const uint2*)(h0b + (size_t)rA.x * 64 + fq * 4);
                uint2 uB = *(const uint2*)(h0b + (size_t)rB.x * 64 + fq * 4);
                a0[0] += valA * __uint_as_float(uA.x << 16);
                a0[1] += valA * __uint_as_float(uA.x & 0xFFFF0000u);
                a0[2] += valA * __uint_as_float(uA.y << 16);
                a0[3] += valA * __uint_as_float(uA.y & 0xFFFF0000u);
                a1[0] += valB * __uint_as_float(uB.x << 16);
                a1[1] += valB * __uint_as_float(uB.x & 0xFFFF0000u);
                a1[2] += valB * __uint_as_float(uB.y << 16);
                a1[3] += valB * __uint_as_float(uB.y & 0xFFFF0000u);
            }
#pragma unroll
            for (int k = 0; k < 4; ++k) {
                float vv = a0[k] + a1[k];
                vv += __shfl_xor(vv, 16);
                vv += __shfl_xor(vv, 32);
                a0[k] = vv;
            }
            float inv = (e2 > s) ? 1.0f / hsumS[n] : 0.f;
            if (lane < 16) {
                float4 o;
                o.x = a0[0] * inv; o.y = a0[1] * inv;
                o.z = a0[2] * inv; o.w = a0[3] * inv;
                *(float4*)&out[(size_t)(n0 + n) * 64 + fq * 4] = o;
            }
            if (lane == 0) inv_hsum_g[n0 + n] = inv;
        }
    } else {
        // correctness-only fallback (cnt > CAPB is ~16 sigma; never expected)
        __syncthreads();
        for (int n = wv; n < nn; n += 4) {
            float acc = 0.f;
            for (int seg = 0; seg < NEB; ++seg) {
                size_t o = (size_t)seg * (NB + 1) + b;
                int st = segpref[o], en = segpref[o + 1];
                for (int i = st; i < en; ++i) {
                    int2 rr = binned[(size_t)seg * EPB + i];
                    if ((int)((unsigned)rr.x >> 24) == n)
                        acc += __uint_as_float((unsigned)rr.y << 16) *
                               bf2f(h0b[(size_t)(rr.x & 0xFFFFFF) * 64 + lane]);
                }
            }
            float hs = hsumS[n];
            float inv = (hs > 0.f) ? 1.0f / hs : 0.f;
            out[(size_t)(n0 + n) * 64 + lane] = acc * inv;
            if (lane == 0) inv_hsum_g[n0 + n] = inv;
        }
    }
}

// ---------------------------------------------------------------------------
// K4: alpha[e] = h(e) * inv_hsum[src[e]]  (h recomputed; coalesced, x4)
__global__ __launch_bounds__(256) void k_alpha(
    const int* __restrict__ src, const int* __restrict__ dst,
    const float* __restrict__ s_src, const float* __restrict__ s_dst,
    const float* __restrict__ inv_hsum_g, float* __restrict__ alpha, int E)
{
    int i = blockIdx.x * 256 + threadIdx.x;
    int e = i * 4;
    if (e + 3 < E) {
        int4 s4 = *(const int4*)&src[e];
        int4 d4 = *(const int4*)&dst[e];
        float4 a;
        a.x = leaky_exp(s_src[s4.x] + s_dst[d4.x]) * inv_hsum_g[s4.x];
        a.y = leaky_exp(s_src[s4.y] + s_dst[d4.y]) * inv_hsum_g[s4.y];
        a.z = leaky_exp(s_src[s4.z] + s_dst[d4.z]) * inv_hsum_g[s4.z];
        a.w = leaky_exp(s_src[s4.w] + s_dst[d4.w]) * inv_hsum_g[s4.w];
        *(float4*)&alpha[e] = a;
    } else {
        for (; e < E; ++e)
            alpha[e] = leaky_exp(s_src[src[e]] + s_dst[dst[e]]) * inv_hsum_g[src[e]];
    }
}

// ---------------------------------------------------------------------------
extern "C" void kernel_launch(void* const* d_in, const int* in_sizes, int n_in,
                              void* d_out, int out_size, void* d_ws, size_t ws_size,
                              hipStream_t stream)
{
    const float* x    = (const float*)d_in[0];
    const int*   ei   = (const int*)d_in[1];
    const float* adj  = (const float*)d_in[2];
    const float* fc_w = (const float*)d_in[3];
    const float* a_w  = (const float*)d_in[4];
    const float* a_b  = (const float*)d_in[5];

    const int N = in_sizes[0] / 128;          // 100000
    const int E = in_sizes[2];                // 1600000
    const int* src = ei;
    const int* dst = ei + E;

    const int NB  = (N + BSZ - 1) >> BSH;     // 1563 buckets
    const int NEB = (E + EPB - 1) / EPB;      // 391 segments

    float* out   = (float*)d_out;
    float* alpha = out + (size_t)N * 64;

    char* w = (char*)d_ws;
    auto carve = [&](size_t bytes) {
        char* p = w;
        w += (bytes + 255) & ~(size_t)255;
        return p;
    };
    unsigned short* h0b = (unsigned short*)carve((size_t)N * 64 * 2);
    float* s_src   = (float*)carve((size_t)N * 4);
    float* s_dst   = (float*)carve((size_t)N * 4);
    float* inv_hs  = (float*)carve((size_t)N * 4);
    int*   segpref = (int*)  carve((size_t)NEB * (NB + 1) * 4);
    int2*  binned  = (int2*) carve((size_t)E * 8);

    const int tiles = (N + 15) / 16;
    const int lgrid = (tiles + 3) / 4;         // 1563

    k_linear_mfma<<<lgrid, 256, 0, stream>>>(x, fc_w, a_w, a_b, h0b,
                                             s_src, s_dst, N);
    k_bin<<<NEB, 256, 0, stream>>>(src, dst, adj, s_src, s_dst,
                                   binned, segpref, E, NB);
    k_bucket<<<NB, 256, 0, stream>>>(binned, segpref, h0b, out, inv_hs,
                                     N, NEB, NB);
    k_alpha<<<(E / 4 + 255) / 256, 256, 0, stream>>>(src, dst, s_src, s_dst,
                                                     inv_hs, alpha, E);
}